// Round 3
// baseline (1531.241 us; speedup 1.0000x reference)
//
#include <hip/hip_runtime.h>
#include <math.h>

// B=4, N=1024, C=768, H=12, D=64
// ws (floats): q[3145728] k[3145728] qpk kpk vpk (u32 views) qgrh kgrh (ushort) qn4 kn4
// attno aliases q (q f32 dead after qr/row_norms).

typedef __attribute__((ext_vector_type(8))) short short8;
typedef __attribute__((ext_vector_type(4))) float f32x4;

__device__ __forceinline__ unsigned bf16r(float x) {
    unsigned u = __float_as_uint(x);
    return (u + 0x7FFFu + ((u >> 16) & 1u)) >> 16;
}
__device__ __forceinline__ unsigned packhl(float x) {
    unsigned u = __float_as_uint(x);
    unsigned hi = (u + 0x7FFFu + ((u >> 16) & 1u)) & 0xFFFF0000u;
    float lo = x - __uint_as_float(hi);
    unsigned ul = __float_as_uint(lo);
    unsigned l16 = (ul + 0x7FFFu + ((ul >> 16) & 1u)) >> 16;
    return hi | (l16 & 0xFFFFu);
}
union U4S8 { uint4 u; short8 s; };
__device__ __forceinline__ short8 mk_hi(uint4 a, uint4 b) {
    U4S8 r;
    r.u.x = __builtin_amdgcn_perm(a.y, a.x, 0x07060302);
    r.u.y = __builtin_amdgcn_perm(a.w, a.z, 0x07060302);
    r.u.z = __builtin_amdgcn_perm(b.y, b.x, 0x07060302);
    r.u.w = __builtin_amdgcn_perm(b.w, b.z, 0x07060302);
    return r.s;
}
__device__ __forceinline__ short8 mk_lo(uint4 a, uint4 b) {
    U4S8 r;
    r.u.x = __builtin_amdgcn_perm(a.y, a.x, 0x05040100);
    r.u.y = __builtin_amdgcn_perm(a.w, a.z, 0x05040100);
    r.u.z = __builtin_amdgcn_perm(b.y, b.x, 0x05040100);
    r.u.w = __builtin_amdgcn_perm(b.w, b.z, 0x05040100);
    return r.s;
}
#define MFMA(a,b,c) __builtin_amdgcn_mfma_f32_16x16x32_bf16(a, b, c, 0, 0, 0)

// ---------------- K1: qkv GEMM + scatter (f32 + packed hi/lo bf16) ----------------
__global__ __launch_bounds__(256) void qkv_gemm(
    const float* __restrict__ x, const float* __restrict__ w, const float* __restrict__ bias,
    float* __restrict__ q, float* __restrict__ k,
    unsigned* __restrict__ qpk, unsigned* __restrict__ kpk, unsigned* __restrict__ vpk)
{
    __shared__ float As[16][68];
    __shared__ float Ws[16][68];
    const int tid = threadIdx.x;
    const int m0 = blockIdx.x * 64;
    const int c0 = blockIdx.y * 64;
    const int ty = tid >> 4, tx = tid & 15;
    const int lm = tid >> 2;
    const int lk = (tid & 3) * 4;
    float acc[4][4];
#pragma unroll
    for (int i = 0; i < 4; i++)
#pragma unroll
        for (int j = 0; j < 4; j++) acc[i][j] = 0.f;

    for (int kk0 = 0; kk0 < 768; kk0 += 16) {
        float4 av = *(const float4*)&x[(m0 + lm) * 768 + kk0 + lk];
        float4 wv = *(const float4*)&w[(c0 + lm) * 768 + kk0 + lk];
        __syncthreads();
        As[lk + 0][lm] = av.x; As[lk + 1][lm] = av.y; As[lk + 2][lm] = av.z; As[lk + 3][lm] = av.w;
        Ws[lk + 0][lm] = wv.x; Ws[lk + 1][lm] = wv.y; Ws[lk + 2][lm] = wv.z; Ws[lk + 3][lm] = wv.w;
        __syncthreads();
#pragma unroll
        for (int kk = 0; kk < 16; kk++) {
            float4 a  = *(const float4*)&As[kk][ty * 4];
            float4 bv = *(const float4*)&Ws[kk][tx * 4];
            acc[0][0] += a.x * bv.x; acc[0][1] += a.x * bv.y; acc[0][2] += a.x * bv.z; acc[0][3] += a.x * bv.w;
            acc[1][0] += a.y * bv.x; acc[1][1] += a.y * bv.y; acc[1][2] += a.y * bv.z; acc[1][3] += a.y * bv.w;
            acc[2][0] += a.z * bv.x; acc[2][1] += a.z * bv.y; acc[2][2] += a.z * bv.z; acc[2][3] += a.z * bv.w;
            acc[3][0] += a.w * bv.x; acc[3][1] += a.w * bv.y; acc[3][2] += a.w * bv.z; acc[3][3] += a.w * bv.w;
        }
    }
#pragma unroll
    for (int i = 0; i < 4; i++) {
        int row = m0 + ty * 4 + i;
        int bb = row >> 10, n = row & 1023;
#pragma unroll
        for (int j = 0; j < 4; j++) {
            int col = c0 + tx * 4 + j;
            float val = acc[i][j] + bias[col];
            int s = (col >= 1536) ? 2 : ((col >= 768) ? 1 : 0);
            int hc = col - s * 768;
            size_t idx = ((size_t)(bb * 12 + (hc >> 6)) << 16) + ((size_t)n << 6) + (hc & 63);
            if (s == 0)      { q[idx] = val; qpk[idx] = packhl(val); }
            else if (s == 1) { k[idx] = val; kpk[idx] = packhl(val); }
            else             { vpk[idx] = packhl(val); }
        }
    }
}

// ---------------- K1b: squared row norms (qn2^2, kn2^2) ----------------
__global__ __launch_bounds__(256) void row_norms(
    const float* __restrict__ q, const float* __restrict__ k,
    float* __restrict__ qn4, float* __restrict__ kn4)
{
    int wid = blockIdx.x * 4 + (threadIdx.x >> 6);
    int lane = threadIdx.x & 63;
    const float* src; float* dst; int r;
    if (wid < 49152) { src = q; dst = qn4; r = wid; }
    else             { src = k; dst = kn4; r = wid - 49152; }
    float xv = src[(size_t)r * 64 + lane];
    float s = xv * xv;
#pragma unroll
    for (int m = 1; m < 64; m <<= 1) s += __shfl_xor(s, m, 64);
    if (lane == 0) dst[r] = s * s;
}

// ---------------- K2: Householder QR (LAPACK signs), bf16 output ----------------
__global__ __launch_bounds__(1024) void qr_kernel(
    const float* __restrict__ q, const float* __restrict__ k,
    unsigned short* __restrict__ qgrh, unsigned short* __restrict__ kgrh)
{
    const int id = blockIdx.x;
    const float* src = (id & 1) ? k : q;
    unsigned short* dst = (id & 1) ? kgrh : qgrh;
    const int bh = id >> 1;
    src += (size_t)bh << 16;
    dst += (size_t)bh << 16;
    const int lane = threadIdx.x & 63;
    const int w = threadIdx.x >> 6;
    __shared__ float vbuf[1024];
    __shared__ float taub[64];

    float a[4][16];
#pragma unroll
    for (int c = 0; c < 4; c++)
#pragma unroll
        for (int i = 0; i < 16; i++)
            a[c][i] = src[(i * 64 + lane) * 64 + 4 * w + c];

    for (int d = 0; d < 64; d++) {
        const int wd = d >> 2, cd = d & 3;
        if (w == wd) {
#pragma unroll
            for (int c = 0; c < 4; c++) if (c == cd) {
                float part = 0.f;
#pragma unroll
                for (int i = 0; i < 16; i++) {
                    int r = i * 64 + lane; float xx = a[c][i];
                    part += (r >= d) ? xx * xx : 0.f;
                }
#pragma unroll
                for (int m = 1; m < 64; m <<= 1) part += __shfl_xor(part, m, 64);
                float sigma = part;
                float xd = __shfl(a[c][0], d, 64);
                float nrm = sqrtf(sigma);
                float beta = (xd >= 0.f) ? -nrm : nrm;
                float vd = xd - beta;
                float vtv = (sigma - xd * xd) + vd * vd;
                float tau2 = (vtv > 0.f) ? 2.f / vtv : 0.f;
                if (lane == d) a[c][0] = vd;
#pragma unroll
                for (int i = 0; i < 16; i++) {
                    int r = i * 64 + lane;
                    vbuf[r] = (r < d) ? 0.f : a[c][i];
                }
                if (lane == 0) taub[d] = tau2;
            }
        }
        __syncthreads();
        float t2 = taub[d];
#pragma unroll
        for (int c = 0; c < 4; c++) {
            int j = 4 * w + c;
            if (j > d) {
                float part = 0.f;
#pragma unroll
                for (int i = 0; i < 16; i++) part += vbuf[i * 64 + lane] * a[c][i];
#pragma unroll
                for (int m = 1; m < 64; m <<= 1) part += __shfl_xor(part, m, 64);
                float sv = t2 * part;
#pragma unroll
                for (int i = 0; i < 16; i++) a[c][i] -= sv * vbuf[i * 64 + lane];
            }
        }
        __syncthreads();
    }

    float qr[4][16];
#pragma unroll
    for (int c = 0; c < 4; c++)
#pragma unroll
        for (int i = 0; i < 16; i++) {
            int r = i * 64 + lane;
            qr[c][i] = (r == 4 * w + c) ? 1.f : 0.f;
        }
    for (int d = 63; d >= 0; d--) {
        const int wd = d >> 2, cd = d & 3;
        if (w == wd) {
#pragma unroll
            for (int c = 0; c < 4; c++) if (c == cd) {
#pragma unroll
                for (int i = 0; i < 16; i++) {
                    int r = i * 64 + lane;
                    vbuf[r] = (r < d) ? 0.f : a[c][i];
                }
            }
        }
        __syncthreads();
        float t2 = taub[d];
#pragma unroll
        for (int c = 0; c < 4; c++) {
            int j = 4 * w + c;
            if (j >= d) {
                float part = 0.f;
#pragma unroll
                for (int i = 0; i < 16; i++) part += vbuf[i * 64 + lane] * qr[c][i];
#pragma unroll
                for (int m = 1; m < 64; m <<= 1) part += __shfl_xor(part, m, 64);
                float sv = t2 * part;
#pragma unroll
                for (int i = 0; i < 16; i++) qr[c][i] -= sv * vbuf[i * 64 + lane];
            }
        }
        __syncthreads();
    }
#pragma unroll
    for (int c = 0; c < 4; c++)
#pragma unroll
        for (int i = 0; i < 16; i++)
            dst[(i * 64 + lane) * 64 + 4 * w + c] = (unsigned short)bf16r(qr[c][i]);
}

// ---------------- K3: fused MFMA scores -> conv -> BN -> online softmax -> PV ----------------
// 512 thr = 8 waves; NT=16 q-rows, MT=128 m-cols per step; all 12 heads.
// LDS 158816 B -> 1 block/CU. launch_bounds(512,1): 2 waves/SIMD, 256-VGPR budget (no spill).
#define SM_BYTES 158816
__global__ __launch_bounds__(512, 1) void attn_fused(
    const unsigned* __restrict__ qpk, const unsigned* __restrict__ kpk, const unsigned* __restrict__ vpk,
    const unsigned short* __restrict__ qgrh, const unsigned short* __restrict__ kgrh,
    const float* __restrict__ qn4g, const float* __restrict__ kn4g,
    const float* __restrict__ cw, const float* __restrict__ conv_b,
    const float* __restrict__ bn_gamma, const float* __restrict__ bn_beta,
    const float* __restrict__ bn_mean, const float* __restrict__ bn_var,
    const float* __restrict__ scale_p, const float* __restrict__ riem_p,
    const float* __restrict__ grass_p, float* __restrict__ attno)
{
    extern __shared__ char smem[];
    unsigned* qs   = (unsigned*)(smem);
    unsigned short* qgs  = (unsigned short*)(smem + 49152);
    unsigned* kL   = (unsigned*)(smem + 73728);
    unsigned short* kgrL = (unsigned short*)(smem + 106496);
    unsigned short* P_s  = (unsigned short*)(smem + 73728);
    unsigned* vt_s = (unsigned*)(smem + 122880);
    float* red     = (float*)(smem + 122880);
    float* mb      = (float*)(smem + 122880);
    float* Abn_s   = (float*)(smem + 155648);
    float* Bbn_s   = Abn_s + 12;
    float* qn4s    = Bbn_s + 12;
    float* mrun_s  = qn4s + 192;
    float* lrun_s  = mrun_s + 192;
    float* coS_s   = lrun_s + 192;

    const int tid = threadIdx.x;
    const int lane = tid & 63;
    const int w = tid >> 6;
    const int rowL = lane & 15;
    const int g = lane >> 4;
    const int r7 = rowL & 7;
    const int b = blockIdx.y;
    const int n0 = blockIdx.x * 16;
    const float scale = scale_p[0], riem_scale = riem_p[0], grass_scale = grass_p[0];

    if (tid >= 192 && tid < 204) {
        int o = tid - 192;
        float inv = bn_gamma[o] * rsqrtf(bn_var[o] + 1e-5f);
        Abn_s[o] = inv;
        Bbn_s[o] = fmaf(conv_b[o] - bn_mean[o], inv, bn_beta[o]);
    }
    if (tid < 192) {
        mrun_s[tid] = -1e30f; lrun_s[tid] = 0.f;
        qn4s[tid] = qn4g[(size_t)(b * 12 + (tid >> 4)) * 1024 + n0 + (tid & 15)];
    }
    // stage q packed + qgr (once)
#pragma unroll
    for (int e = 0; e < 6; e++) {
        int ci = tid + 512 * e;
        int R = ci >> 4, c = ci & 15;
        const unsigned* gp = qpk + ((size_t)(b * 12 + (R >> 4)) << 16) + (size_t)(n0 + (R & 15)) * 64 + c * 4;
        uint4 v = *(const uint4*)gp;
        *(uint4*)&qs[R * 64 + ((c ^ (R & 7)) << 2)] = v;
    }
#pragma unroll
    for (int e = 0; e < 3; e++) {
        int ci = tid + 512 * e;
        int R = ci >> 3, c = ci & 7;
        const unsigned short* gp = qgrh + ((size_t)(b * 12 + (R >> 4)) << 16) + (size_t)(n0 + (R & 15)) * 64 + c * 8;
        uint4 v = *(const uint4*)gp;
        *(uint4*)&qgs[R * 64 + ((c ^ (R & 7)) << 3)] = v;
    }

    f32x4 y[12], acc[12];
#pragma unroll
    for (int o = 0; o < 12; o++) { y[o] = (f32x4){0,0,0,0}; acc[o] = (f32x4){0,0,0,0}; }

    uint4 kreg[4], kgreg[2], vreg[4];
    // preload k tile (m0=0, h=0)
    {
        const unsigned* kp = kpk + ((size_t)(b * 12) << 16);
        const unsigned short* kg = kgrh + ((size_t)(b * 12) << 16);
#pragma unroll
        for (int e = 0; e < 4; e++) { int ci = tid + 512 * e; kreg[e] = *(const uint4*)&kp[(size_t)(ci >> 4) * 64 + (ci & 15) * 4]; }
#pragma unroll
        for (int e = 0; e < 2; e++) { int ci = tid + 512 * e; kgreg[e] = *(const uint4*)&kg[(size_t)(ci >> 3) * 64 + (ci & 7) * 8]; }
    }

    for (int m0 = 0; m0 < 1024; m0 += 128) {
        // ---------- scores over 12 heads ----------
        for (int h = 0; h < 12; h++) {
            // write k tile to LDS from regs
#pragma unroll
            for (int e = 0; e < 4; e++) {
                int ci = tid + 512 * e; int m = ci >> 4, c = ci & 15;
                *(uint4*)&kL[m * 64 + ((c ^ (m & 7)) << 2)] = kreg[e];
            }
#pragma unroll
            for (int e = 0; e < 2; e++) {
                int ci = tid + 512 * e; int m = ci >> 3, c = ci & 7;
                *(uint4*)&kgrL[m * 64 + ((c ^ (m & 7)) << 3)] = kgreg[e];
            }
            if (h < 11) {
                const unsigned* kp = kpk + ((size_t)(b * 12 + h + 1) << 16) + (size_t)m0 * 64;
                const unsigned short* kg = kgrh + ((size_t)(b * 12 + h + 1) << 16) + (size_t)m0 * 64;
#pragma unroll
                for (int e = 0; e < 4; e++) { int ci = tid + 512 * e; kreg[e] = *(const uint4*)&kp[(size_t)(ci >> 4) * 64 + (ci & 15) * 4]; }
#pragma unroll
                for (int e = 0; e < 2; e++) { int ci = tid + 512 * e; kgreg[e] = *(const uint4*)&kg[(size_t)(ci >> 3) * 64 + (ci & 7) * 8]; }
            }
            __syncthreads();

            float kn4v = kn4g[(size_t)(b * 12 + h) * 1024 + m0 + w * 16 + rowL];
            short8 qhiF[2], qloF[2], khiF[2], kloF[2], qgF[2], kgF[2];
#pragma unroll
            for (int ks = 0; ks < 2; ks++) {
                int c0 = ks * 8 + g * 2;
                const unsigned* qrow = &qs[(h * 16 + rowL) * 64];
                uint4 a0 = *(const uint4*)&qrow[((c0 ^ r7) << 2)];
                uint4 a1 = *(const uint4*)&qrow[(((c0 + 1) ^ r7) << 2)];
                qhiF[ks] = mk_hi(a0, a1); qloF[ks] = mk_lo(a0, a1);
                const unsigned* krow = &kL[(w * 16 + rowL) * 64];
                uint4 b0 = *(const uint4*)&krow[((c0 ^ r7) << 2)];
                uint4 b1 = *(const uint4*)&krow[(((c0 + 1) ^ r7) << 2)];
                khiF[ks] = mk_hi(b0, b1); kloF[ks] = mk_lo(b0, b1);
                int cg = ks * 4 + g;
                qgF[ks] = *(const short8*)&qgs[(h * 16 + rowL) * 64 + ((cg ^ r7) << 3)];
                kgF[ks] = *(const short8*)&kgrL[(w * 16 + rowL) * 64 + ((cg ^ r7) << 3)];
            }
            f32x4 s1 = {0,0,0,0}, s2 = {0,0,0,0};
#pragma unroll
            for (int ks = 0; ks < 2; ks++) {
                s1 = MFMA(qhiF[ks], khiF[ks], s1);
                s1 = MFMA(qhiF[ks], kloF[ks], s1);
                s1 = MFMA(qloF[ks], khiF[ks], s1);
                s2 = MFMA(qgF[ks], kgF[ks], s2);
            }
#pragma unroll
            for (int r = 0; r < 4; r++) {
                float qk = s1[r], gr = s2[r];
                float qn4v = qn4s[h * 16 + g * 4 + r];
                float att = qk * scale;
                float d2 = qn4v + kn4v - 2.f * qk * qk;
                float rie = -sqrtf(fmaxf(d2, 0.f) + 1e-8f) * riem_scale;
                float gra = gr * gr * grass_scale;
#pragma unroll
                for (int o = 0; o < 12; o++)
                    y[o][r] = fmaf(cw[o * 36 + h], att,
                               fmaf(cw[o * 36 + 12 + h], rie,
                                fmaf(cw[o * 36 + 24 + h], gra, y[o][r])));
            }
            __syncthreads();
        }

        // ---------- batched BN + online softmax ----------
        // issue v loads for o=0 (transposed-friendly pattern: d=tid&63, 4 m each)
        {
            const unsigned* vp = vpk + ((size_t)(b * 12) << 16) + (size_t)m0 * 64;
            int d = tid & 63;
#pragma unroll
            for (int e = 0; e < 4; e++) {
                int mbase = (tid >> 6) * 4 + 32 * e;
                vreg[e].x = vp[(size_t)(mbase + 0) * 64 + d];
                vreg[e].y = vp[(size_t)(mbase + 1) * 64 + d];
                vreg[e].z = vp[(size_t)(mbase + 2) * 64 + d];
                vreg[e].w = vp[(size_t)(mbase + 3) * 64 + d];
            }
        }
#pragma unroll
        for (int o = 0; o < 12; o++) {
#pragma unroll
            for (int r = 0; r < 4; r++) {
                float yv = fmaf(y[o][r], Abn_s[o], Bbn_s[o]);
                y[o][r] = yv;
                float mx = yv;
                mx = fmaxf(mx, __shfl_xor(mx, 1, 64));
                mx = fmaxf(mx, __shfl_xor(mx, 2, 64));
                mx = fmaxf(mx, __shfl_xor(mx, 4, 64));
                mx = fmaxf(mx, __shfl_xor(mx, 8, 64));
                if (rowL == 0) red[(o * 16 + g * 4 + r) * 8 + w] = mx;
            }
        }
        __syncthreads(); // B1
        if (tid < 192) {
            float m8 = red[tid * 8];
#pragma unroll
            for (int j = 1; j < 8; j++) m8 = fmaxf(m8, red[tid * 8 + j]);
            float mo = mrun_s[tid];
            float mn = fmaxf(mo, m8);
            mrun_s[tid] = mn;
            coS_s[tid] = expf(mo - mn);
        }
        __syncthreads(); // B2
#pragma unroll
        for (int o = 0; o < 12; o++) {
#pragma unroll
            for (int r = 0; r < 4; r++) {
                int row = g * 4 + r;
                float mn = mrun_s[o * 16 + row];
                float p = expf(y[o][r] - mn);
                unsigned us = bf16r(p);
                float pr = __uint_as_float(us << 16);
                int m = w * 16 + rowL;
                P_s[(o * 16 + row) * 128 + ((((m >> 3) ^ (row & 7))) << 3) + (m & 7)] = (unsigned short)us;
                float s = pr;
                s += __shfl_xor(s, 1, 64); s += __shfl_xor(s, 2, 64);
                s += __shfl_xor(s, 4, 64); s += __shfl_xor(s, 8, 64);
                if (rowL == 0) red[(o * 16 + row) * 8 + w] = s;
                y[o][r] = 0.f;
            }
        }
        __syncthreads(); // B3
        if (tid < 192) {
            float s8 = 0.f;
#pragma unroll
            for (int j = 0; j < 8; j++) s8 += red[tid * 8 + j];
            lrun_s[tid] = fmaf(lrun_s[tid], coS_s[tid], s8);
        }
        __syncthreads(); // B4

        // ---------- PV over 12 heads ----------
        const int km = w >> 2, wd = w & 3;
#pragma unroll
        for (int o = 0; o < 12; o++) {
            // write V^T tile from regs (swizzle chunk ^ (d&15))
            {
                int d = tid & 63;
#pragma unroll
                for (int e = 0; e < 4; e++) {
                    int mc = (tid >> 6) + 8 * e; // m>>2
                    *(uint4*)&vt_s[d * 128 + ((mc ^ (d & 15)) << 2)] = vreg[e];
                }
            }
            if (o < 11) {
                const unsigned* vp = vpk + ((size_t)(b * 12 + o + 1) << 16) + (size_t)m0 * 64;
                int d = tid & 63;
#pragma unroll
                for (int e = 0; e < 4; e++) {
                    int mbase = (tid >> 6) * 4 + 32 * e;
                    vreg[e].x = vp[(size_t)(mbase + 0) * 64 + d];
                    vreg[e].y = vp[(size_t)(mbase + 1) * 64 + d];
                    vreg[e].z = vp[(size_t)(mbase + 2) * 64 + d];
                    vreg[e].w = vp[(size_t)(mbase + 3) * 64 + d];
                }
            } else if (m0 + 128 < 1024) {
                const unsigned* kp = kpk + ((size_t)(b * 12) << 16) + (size_t)(m0 + 128) * 64;
                const unsigned short* kg = kgrh + ((size_t)(b * 12) << 16) + (size_t)(m0 + 128) * 64;
#pragma unroll
                for (int e = 0; e < 4; e++) { int ci = tid + 512 * e; kreg[e] = *(const uint4*)&kp[(size_t)(ci >> 4) * 64 + (ci & 15) * 4]; }
#pragma unroll
                for (int e = 0; e < 2; e++) { int ci = tid + 512 * e; kgreg[e] = *(const uint4*)&kg[(size_t)(ci >> 3) * 64 + (ci & 7) * 8]; }
            }
            __syncthreads();
#pragma unroll
            for (int r = 0; r < 4; r++) acc[o][r] *= coS_s[o * 16 + g * 4 + r];
#pragma unroll
            for (int ks = 0; ks < 2; ks++) {
                int mc8 = km * 8 + ks * 4 + g;   // m>>3
                short8 pa = *(const short8*)&P_s[(o * 16 + rowL) * 128 + ((mc8 ^ r7) << 3)];
                int c0 = km * 16 + ks * 8 + g * 2; // m>>2
                const unsigned* vrow = &vt_s[(wd * 16 + rowL) * 128];
                uint4 b0 = *(const uint4*)&vrow[((c0 ^ rowL) << 2)];
                uint4 b1 = *(const uint4*)&vrow[(((c0 + 1) ^ rowL) << 2)];
                short8 vh = mk_hi(b0, b1), vl = mk_lo(b0, b1);
                acc[o] = MFMA(pa, vh, acc[o]);
                acc[o] = MFMA(pa, vl, acc[o]);
            }
            __syncthreads();
        }
    }

    // ---------- epilogue: merge km halves, normalize, store ----------
    const int km = w >> 2, wd = w & 3;
#pragma unroll
    for (int o = 0; o < 12; o++) {
        if (km == 1) {
#pragma unroll
            for (int r = 0; r < 4; r++) mb[(g * 4 + r) * 64 + wd * 16 + rowL] = acc[o][r];
        }
        __syncthreads();
        if (km == 0) {
#pragma unroll
            for (int r = 0; r < 4; r++) {
                int row = g * 4 + r;
                float tot = acc[o][r] + mb[row * 64 + wd * 16 + rowL];
                float inv = 1.f / lrun_s[o * 16 + row];
                attno[((size_t)(b * 1024 + n0 + row)) * 768 + o * 64 + wd * 16 + rowL] = tot * inv;
            }
        }
        __syncthreads();
    }
}

// ---------------- K4: out = attno @ proj_w^T + proj_b ----------------
__global__ __launch_bounds__(256) void proj_gemm(
    const float* __restrict__ x, const float* __restrict__ w, const float* __restrict__ bias,
    float* __restrict__ out)
{
    __shared__ float As[16][68];
    __shared__ float Ws[16][68];
    const int tid = threadIdx.x;
    const int m0 = blockIdx.x * 64;
    const int c0 = blockIdx.y * 64;
    const int ty = tid >> 4, tx = tid & 15;
    const int lm = tid >> 2;
    const int lk = (tid & 3) * 4;
    float acc[4][4];
#pragma unroll
    for (int i = 0; i < 4; i++)
#pragma unroll
        for (int j = 0; j < 4; j++) acc[i][j] = 0.f;

    for (int kk0 = 0; kk0 < 768; kk0 += 16) {
        float4 av = *(const float4*)&x[(m0 + lm) * 768 + kk0 + lk];
        float4 wv = *(const float4*)&w[(c0 + lm) * 768 + kk0 + lk];
        __syncthreads();
        As[lk + 0][lm] = av.x; As[lk + 1][lm] = av.y; As[lk + 2][lm] = av.z; As[lk + 3][lm] = av.w;
        Ws[lk + 0][lm] = wv.x; Ws[lk + 1][lm] = wv.y; Ws[lk + 2][lm] = wv.z; Ws[lk + 3][lm] = wv.w;
        __syncthreads();
#pragma unroll
        for (int kk = 0; kk < 16; kk++) {
            float4 a  = *(const float4*)&As[kk][ty * 4];
            float4 bv = *(const float4*)&Ws[kk][tx * 4];
            acc[0][0] += a.x * bv.x; acc[0][1] += a.x * bv.y; acc[0][2] += a.x * bv.z; acc[0][3] += a.x * bv.w;
            acc[1][0] += a.y * bv.x; acc[1][1] += a.y * bv.y; acc[1][2] += a.y * bv.z; acc[1][3] += a.y * bv.w;
            acc[2][0] += a.z * bv.x; acc[2][1] += a.z * bv.y; acc[2][2] += a.z * bv.z; acc[2][3] += a.z * bv.w;
            acc[3][0] += a.w * bv.x; acc[3][1] += a.w * bv.y; acc[3][2] += a.w * bv.z; acc[3][3] += a.w * bv.w;
        }
    }
#pragma unroll
    for (int i = 0; i < 4; i++) {
        int row = m0 + ty * 4 + i;
#pragma unroll
        for (int j = 0; j < 4; j++) {
            int col = c0 + tx * 4 + j;
            out[(size_t)row * 768 + col] = acc[i][j] + bias[col];
        }
    }
}

extern "C" void kernel_launch(void* const* d_in, const int* in_sizes, int n_in,
                              void* d_out, int out_size, void* d_ws, size_t ws_size,
                              hipStream_t stream) {
    const float* x          = (const float*)d_in[0];
    const float* qkv_w      = (const float*)d_in[1];
    const float* qkv_b      = (const float*)d_in[2];
    const float* proj_w     = (const float*)d_in[3];
    const float* proj_b     = (const float*)d_in[4];
    const float* scale      = (const float*)d_in[5];
    const float* riem_scale = (const float*)d_in[6];
    const float* grass_scale= (const float*)d_in[7];
    const float* conv_w     = (const float*)d_in[8];
    const float* conv_b     = (const float*)d_in[9];
    const float* bn_gamma   = (const float*)d_in[10];
    const float* bn_beta    = (const float*)d_in[11];
    const float* bn_mean    = (const float*)d_in[12];
    const float* bn_var     = (const float*)d_in[13];
    float* out = (float*)d_out;

    float* q   = (float*)d_ws;                 // 3145728 f32 ; later aliased as attno
    float* k   = q + 3145728;
    unsigned* qpk = (unsigned*)(k + 3145728);
    unsigned* kpk = qpk + 3145728;
    unsigned* vpk = kpk + 3145728;
    unsigned short* qgrh = (unsigned short*)(vpk + 3145728);
    unsigned short* kgrh = qgrh + 3145728;
    float* qn4 = (float*)(kgrh + 3145728);
    float* kn4 = qn4 + 49152;
    float* attno = q; // alias: q f32 dead after qr_kernel/row_norms

    hipLaunchKernelGGL(qkv_gemm, dim3(64, 36), dim3(256), 0, stream,
                       x, qkv_w, qkv_b, q, k, qpk, kpk, vpk);
    hipLaunchKernelGGL(row_norms, dim3(24576), dim3(256), 0, stream, q, k, qn4, kn4);
    hipLaunchKernelGGL(qr_kernel, dim3(96), dim3(1024), 0, stream, q, k, qgrh, kgrh);

    hipFuncSetAttribute(reinterpret_cast<const void*>(attn_fused),
                        hipFuncAttributeMaxDynamicSharedMemorySize, SM_BYTES);
    hipLaunchKernelGGL(attn_fused, dim3(64, 4), dim3(512), SM_BYTES, stream,
                       qpk, kpk, vpk, qgrh, kgrh, qn4, kn4, conv_w, conv_b,
                       bn_gamma, bn_beta, bn_mean, bn_var,
                       scale, riem_scale, grass_scale, attno);
    hipLaunchKernelGGL(proj_gemm, dim3(64, 12), dim3(256), 0, stream,
                       attno, proj_w, proj_b, out);
}